// Round 7
// baseline (195.776 us; speedup 1.0000x reference)
//
#include <hip/hip_runtime.h>
#include <hip/hip_bf16.h>

#define BB 2
#define CC 2
#define NN 1024
#define F0V 64
#define HH 8
#define FFV 64
#define BCHN (BB*CC*HH)          // 32
#define SVN  (BB*CC*HH*NN)       // 32768

typedef _Float16 f16x8 __attribute__((ext_vector_type(8)));
typedef _Float16 f16x4 __attribute__((ext_vector_type(4)));
typedef __fp16 h16x2 __attribute__((ext_vector_type(2)));   // cvt_pkrtz native type
typedef float f32x4 __attribute__((ext_vector_type(4)));

// ---------------- Fused prep: convert_x | transpose w1 | transpose w2 | build_mask ----------------
// grid 656 blocks x 256 thr:
//   [0,256)    convert x fp32 -> f16
//   [256,272)  transpose w1 (16 ch, K=64, 1 k-tile)
//   [272,400)  transpose w2 (16 ch x 8 k-tiles, K=512)
//   [400,656)  build adjacency bitmask
__global__ __launch_bounds__(256) void prep_kernel(
    const float* __restrict__ x, const int* __restrict__ adj,
    const float* __restrict__ w1, const float* __restrict__ w2,
    _Float16* __restrict__ xh, _Float16* __restrict__ w1T, _Float16* __restrict__ w2T,
    unsigned long long* __restrict__ bmg)
{
  __shared__ __align__(16) _Float16 tile[64*72];
  const int bx = blockIdx.x;
  const int t = threadIdx.x;
  if (bx < 256) {
    const int i = bx*256 + t;
    const float4 v = ((const float4*)x)[i];
    f16x4 o; o[0]=(_Float16)v.x; o[1]=(_Float16)v.y; o[2]=(_Float16)v.z; o[3]=(_Float16)v.w;
    ((f16x4*)xh)[i] = o;
  } else if (bx < 400) {
    // transpose branch
    int ch, k0, K; const float* w; _Float16* wT;
    if (bx < 272) { ch = bx - 256; k0 = 0; K = 64; w = w1; wT = w1T; }
    else { const int u = bx - 272; ch = u >> 3; k0 = (u & 7)*64; K = 512; w = w2; wT = w2T; }
    const float* src = w + ((size_t)ch*K + k0)*64;
    #pragma unroll
    for (int j = 0; j < 4; ++j) {
      const int u = t + j*256;
      const int k = u >> 4, seg = u & 15;
      const float4 v = ((const float4*)src)[(size_t)k*16 + seg];
      tile[(seg*4+0)*72 + k] = (_Float16)v.x;
      tile[(seg*4+1)*72 + k] = (_Float16)v.y;
      tile[(seg*4+2)*72 + k] = (_Float16)v.z;
      tile[(seg*4+3)*72 + k] = (_Float16)v.w;
    }
    __syncthreads();
    _Float16* dst = wT + (size_t)ch*64*K + k0;
    #pragma unroll
    for (int j = 0; j < 2; ++j) {
      const int u = t + j*256;
      const int f = u >> 3, seg = u & 7;
      const f16x8 o = *(const f16x8*)&tile[f*72 + seg*8];
      *(f16x8*)(dst + (size_t)f*K + seg*8) = o;
    }
  } else {
    const int wg = (bx - 400)*4 + (t >> 6);
    const int lane = t & 63;
    for (int idx = wg; idx < BB*NN*16; idx += 1024) {
      const int b = idx >> 14;
      const int n = (idx >> 4) & (NN - 1);
      const int word = idx & 15;
      const int m = word*64 + lane;
      const int pred = (adj[((size_t)b*NN + n)*NN + m] != 0) || (m == n);
      unsigned long long bits = __ballot(pred);
      if (lane == 0) bmg[idx] = bits;
    }
  }
}

// ---------------- Projection via MFMA: C[32 rows][64 f] = A[rows][K] @ wT[f][K]^T ----------------
template<int K>
__global__ __launch_bounds__(256) void proj_mfma(
    const _Float16* __restrict__ A,      // [bc][N][K]
    const _Float16* __restrict__ wT,     // [c*HH+h][64][K]
    const float* __restrict__ asrc, const float* __restrict__ adst,
    _Float16* __restrict__ HpT, float* __restrict__ s_out, float* __restrict__ d_out)
{
  __shared__ float sp[4][32], sd[4][32];
  const int bch = blockIdx.y;
  const int h = bch % HH; const int bc = bch / HH; const int c = bc % CC;
  const int row0 = blockIdx.x*32;
  const int t = threadIdx.x;
  const int w = t >> 6, lane = t & 63;
  const int colr = lane & 15, quad = lane >> 4;

  const _Float16* Arow0 = A + ((size_t)bc*NN + row0 + colr)*K;
  const _Float16* Arow1 = Arow0 + (size_t)16*K;
  const _Float16* Brow  = wT + ((size_t)(c*HH + h)*64 + w*16 + colr)*K;

  f32x4 acc0 = {0.f,0.f,0.f,0.f}, acc1 = {0.f,0.f,0.f,0.f};
  #pragma unroll 4
  for (int kb = 0; kb < K; kb += 32) {
    const f16x8 a0 = *(const f16x8*)(Arow0 + kb + quad*8);
    const f16x8 a1 = *(const f16x8*)(Arow1 + kb + quad*8);
    const f16x8 bf = *(const f16x8*)(Brow  + kb + quad*8);
    acc0 = __builtin_amdgcn_mfma_f32_16x16x32_f16(a0, bf, acc0, 0, 0, 0);
    acc1 = __builtin_amdgcn_mfma_f32_16x16x32_f16(a1, bf, acc1, 0, 0, 0);
  }

  const float af = asrc[(c*HH + h)*64 + w*16 + colr];
  const float bf_ = adst[(c*HH + h)*64 + w*16 + colr];
  _Float16* HT = HpT + ((size_t)bch*64 + w*16 + colr)*NN + row0;

  #pragma unroll
  for (int mt = 0; mt < 2; ++mt) {
    const f32x4 a = mt ? acc1 : acc0;
    f16x4 hv;
    #pragma unroll
    for (int i = 0; i < 4; ++i) {
      const float v = a[i];
      hv[i] = (_Float16)v;
      const float ex = __expf(2.f*v);
      const float th = 1.f - 2.f/(ex + 1.f);         // tanh(v)
      float ps = th * af, pd = th * bf_;
      #pragma unroll
      for (int off = 1; off < 16; off <<= 1) {
        ps += __shfl_xor(ps, off);
        pd += __shfl_xor(pd, off);
      }
      if (colr == 0) {
        sp[w][mt*16 + quad*4 + i] = ps;
        sd[w][mt*16 + quad*4 + i] = pd;
      }
    }
    *(f16x4*)(HT + mt*16 + quad*4) = hv;
  }
  __syncthreads();
  if (t < 32) {
    const float sv = sp[0][t] + sp[1][t] + sp[2][t] + sp[3][t];
    const float dv = sd[0][t] + sd[1][t] + sd[2][t] + sd[3][t];
    s_out[bch*NN + row0 + t] = sv;
    d_out[bch*NN + row0 + t] = dv;
  }
}

// ---------------- Fused attention v3: 16-row blocks, wave = full 64 f x 256-k quarter ----------
// grid (N/16=64, 32 bch), 256 thr. Lane: row = colr (r<16), k-slice = quad*8 within each 32-k step.
// Explicit 2-stage prefetch of B-frags and d; masks preloaded to registers; no LDS in main loop.
template<int LAYER>
__global__ __launch_bounds__(256) void attn_mfma(
    const _Float16* __restrict__ HpT, const float* __restrict__ s_arr,
    const float* __restrict__ d_arr, const unsigned long long* __restrict__ bmg,
    _Float16* __restrict__ outp)
{
  __shared__ float partials[4*16*68];   // ~17.4 KB, padded stride 68 (2-way bank alias = free)
  __shared__ float dsP[4][16];
  const int bch = blockIdx.y;
  const int b = bch / (CC*HH);
  const int row0 = blockIdx.x*16;
  const int t = threadIdx.x;
  const int w = t >> 6, lane = t & 63;
  const int colr = lane & 15, quad = lane >> 4;

  // per-wave maxd over full d[bch] (no barrier needed)
  const float* dg = d_arr + (size_t)bch*NN;
  const float4* dg4 = (const float4*)dg;
  float mxl = -1e30f;
  #pragma unroll
  for (int j = 0; j < 4; ++j) {
    const float4 v = dg4[lane*4 + j];
    mxl = fmaxf(mxl, fmaxf(fmaxf(v.x, v.y), fmaxf(v.z, v.w)));
  }
  #pragma unroll
  for (int off = 1; off < 64; off <<= 1) mxl = fmaxf(mxl, __shfl_xor(mxl, off));
  const float maxd = mxl;

  const int rowg = row0 + colr;
  const float s0 = s_arr[(size_t)bch*NN + rowg];
  const float so = s0 + maxd;
  const float offs = fmaxf(so, 0.2f*so);          // >= lrelu(s0+d) for all d

  // preload this wave's 4 mask words (256 k bits for row rowg)
  const unsigned long long* bmrow = bmg + ((size_t)b*NN + rowg)*16 + w*4;
  unsigned long long mm[4];
  #pragma unroll
  for (int j = 0; j < 4; ++j) mm[j] = bmrow[j];

  const _Float16* Bg = HpT + (size_t)bch*64*NN;
  f32x4 acc[4];
  #pragma unroll
  for (int ft = 0; ft < 4; ++ft) acc[ft] = (f32x4){0.f,0.f,0.f,0.f};
  float ds0 = 0.f;

  const int kbase = w*256;
  // prefetch kstep 0
  f16x8 Bc0 = *(const f16x8*)(Bg + (size_t)(0*16 + colr)*NN + kbase + quad*8);
  f16x8 Bc1 = *(const f16x8*)(Bg + (size_t)(1*16 + colr)*NN + kbase + quad*8);
  f16x8 Bc2 = *(const f16x8*)(Bg + (size_t)(2*16 + colr)*NN + kbase + quad*8);
  f16x8 Bc3 = *(const f16x8*)(Bg + (size_t)(3*16 + colr)*NN + kbase + quad*8);
  float4 dc0 = *(const float4*)(dg + kbase + quad*8);
  float4 dc1 = *(const float4*)(dg + kbase + quad*8 + 4);

  #pragma unroll
  for (int ks = 0; ks < 8; ++ks) {
    const int kb = kbase + ks*32;
    f16x8 Bn0, Bn1, Bn2, Bn3; float4 dn0, dn1;
    if (ks < 7) {
      const int kn = kb + 32 + quad*8;
      Bn0 = *(const f16x8*)(Bg + (size_t)(0*16 + colr)*NN + kn);
      Bn1 = *(const f16x8*)(Bg + (size_t)(1*16 + colr)*NN + kn);
      Bn2 = *(const f16x8*)(Bg + (size_t)(2*16 + colr)*NN + kn);
      Bn3 = *(const f16x8*)(Bg + (size_t)(3*16 + colr)*NN + kn);
      dn0 = *(const float4*)(dg + kn);
      dn1 = *(const float4*)(dg + kn + 4);
    }
    const unsigned mbyte = (unsigned)((mm[ks >> 1] >> ((ks & 1)*32 + quad*8)) & 0xFFull);
    const float dd[8] = {dc0.x, dc0.y, dc0.z, dc0.w, dc1.x, dc1.y, dc1.z, dc1.w};
    union { f16x8 v; h16x2 h[4]; } A0;
    #pragma unroll
    for (int jp = 0; jp < 4; ++jp) {
      float pv[2];
      #pragma unroll
      for (int jj = 0; jj < 2; ++jj) {
        const int j = jp*2 + jj;
        const float e0 = s0 + dd[j];
        const float l0 = fmaxf(e0, 0.2f*e0);
        const float q0 = ((mbyte >> j) & 1u) ? __expf(l0 - offs) : 0.f;
        ds0 += q0;
        pv[jj] = q0;
      }
      A0.h[jp] = __builtin_amdgcn_cvt_pkrtz(pv[0], pv[1]);
    }
    acc[0] = __builtin_amdgcn_mfma_f32_16x16x32_f16(A0.v, Bc0, acc[0], 0, 0, 0);
    acc[1] = __builtin_amdgcn_mfma_f32_16x16x32_f16(A0.v, Bc1, acc[1], 0, 0, 0);
    acc[2] = __builtin_amdgcn_mfma_f32_16x16x32_f16(A0.v, Bc2, acc[2], 0, 0, 0);
    acc[3] = __builtin_amdgcn_mfma_f32_16x16x32_f16(A0.v, Bc3, acc[3], 0, 0, 0);
    if (ks < 7) { Bc0 = Bn0; Bc1 = Bn1; Bc2 = Bn2; Bc3 = Bn3; dc0 = dn0; dc1 = dn1; }
  }

  // row-denominator partial for this wave's k-quarter (sum over quads)
  ds0 += __shfl_xor(ds0, 16); ds0 += __shfl_xor(ds0, 32);
  if (quad == 0) dsP[w][colr] = ds0;

  // C partials: C/D layout col=colr, row=quad*4+i
  float* pw = partials + w*(16*68);
  #pragma unroll
  for (int ft = 0; ft < 4; ++ft)
    #pragma unroll
    for (int i = 0; i < 4; ++i)
      pw[(quad*4 + i)*68 + ft*16 + colr] = acc[ft][i];
  __syncthreads();

  // final: thread t -> row r = t>>4, features f0 = (t&15)*4
  const int r = t >> 4, f0 = (t & 15)*4;
  const float dsum = dsP[0][r] + dsP[1][r] + dsP[2][r] + dsP[3][r];
  const float inv = 1.f / dsum;
  float4 c = {0.f,0.f,0.f,0.f};
  #pragma unroll
  for (int w4 = 0; w4 < 4; ++w4) {
    const float4 a = *(const float4*)&partials[w4*(16*68) + r*68 + f0];
    c.x += a.x; c.y += a.y; c.z += a.z; c.w += a.w;
  }
  const float cv[4] = {c.x, c.y, c.z, c.w};
  f16x4 o;
  #pragma unroll
  for (int i = 0; i < 4; ++i) {
    float v = cv[i] * inv;
    if (LAYER == 1) v = v > 0.f ? v : expm1f(v);
    o[i] = (_Float16)v;
  }
  const int bc = bch / HH, h = bch % HH;
  if (LAYER == 1)
    *(f16x4*)(outp + ((size_t)bc*NN + row0 + r)*512 + h*64 + f0) = o;
  else
    *(f16x4*)(outp + ((size_t)bch*NN + row0 + r)*64 + f0) = o;
}

// ---------------- Mean over heads (f16 in) -> fp32 out ----------------
__global__ __launch_bounds__(256) void reduce_heads(
    const _Float16* __restrict__ out2, float* __restrict__ out)
{
  const int o = blockIdx.x*256 + threadIdx.x;
  const int f = o & 63;
  const int n = (o >> 6) & (NN - 1);
  const int bc = o >> 16;
  float acc = 0.f;
  #pragma unroll
  for (int h = 0; h < HH; ++h)
    acc += (float)out2[(((size_t)bc*HH + h)*NN + n)*FFV + f];
  out[o] = acc * 0.125f;
}

extern "C" void kernel_launch(void* const* d_in, const int* in_sizes, int n_in,
                              void* d_out, int out_size, void* d_ws, size_t ws_size,
                              hipStream_t stream)
{
  const float* x   = (const float*)d_in[0];
  const int*   adj = (const int*)d_in[1];
  const float* w1  = (const float*)d_in[2];
  const float* as1 = (const float*)d_in[3];
  const float* ad1 = (const float*)d_in[4];
  const float* w2  = (const float*)d_in[5];
  const float* as2 = (const float*)d_in[6];
  const float* ad2 = (const float*)d_in[7];

  char* w8 = (char*)d_ws;
  _Float16* HpT = (_Float16*)(w8);                         // 4 MB  [bch][64][N]
  _Float16* XB  = (_Float16*)(w8 + (4u<<20));              // 4 MB  x1 [bc][N][512] then out2 [bch][N][64]
  _Float16* xh  = (_Float16*)(w8 + (8u<<20));              // 512 KB [bc][N][64]
  _Float16* w1T = (_Float16*)(w8 + (8u<<20) + (512u<<10)); // 128 KB [ch][64][64]
  _Float16* w2T = (_Float16*)(w8 + (8u<<20) + (768u<<10)); // 1 MB   [ch][64][512]
  float* s_v = (float*)(w8 + (10u<<20));                   // 128 KB
  float* d_v = (float*)(w8 + (10u<<20) + SVN*4);           // 128 KB
  unsigned long long* bmg = (unsigned long long*)(w8 + (10u<<20) + SVN*8);  // 256 KB

  prep_kernel<<<656, 256, 0, stream>>>(x, adj, w1, w2, xh, w1T, w2T, bmg);
  proj_mfma<64><<<dim3(NN/32, BCHN), 256, 0, stream>>>(xh, w1T, as1, ad1, HpT, s_v, d_v);
  attn_mfma<1><<<dim3(NN/16, BCHN), 256, 0, stream>>>(HpT, s_v, d_v, bmg, XB);
  proj_mfma<512><<<dim3(NN/32, BCHN), 256, 0, stream>>>(XB, w2T, as2, ad2, HpT, s_v, d_v);
  attn_mfma<2><<<dim3(NN/16, BCHN), 256, 0, stream>>>(HpT, s_v, d_v, bmg, XB);
  reduce_heads<<<dim3((unsigned)(out_size/256)), 256, 0, stream>>>(XB, (float*)d_out);
}

// Round 8
// 164.900 us; speedup vs baseline: 1.1872x; 1.1872x over previous
//
#include <hip/hip_runtime.h>
#include <hip/hip_bf16.h>

#define BB 2
#define CC 2
#define NN 1024
#define F0V 64
#define HH 8
#define FFV 64
#define BCHN (BB*CC*HH)          // 32
#define SVN  (BB*CC*HH*NN)       // 32768

typedef _Float16 f16x8 __attribute__((ext_vector_type(8)));
typedef _Float16 f16x4 __attribute__((ext_vector_type(4)));
typedef __fp16 h16x2 __attribute__((ext_vector_type(2)));   // cvt_pkrtz native type
typedef float f32x4 __attribute__((ext_vector_type(4)));

// ---------------- Fused prep: convert_x | transpose w1 | transpose w2 | build_mask ----------------
__global__ __launch_bounds__(256) void prep_kernel(
    const float* __restrict__ x, const int* __restrict__ adj,
    const float* __restrict__ w1, const float* __restrict__ w2,
    _Float16* __restrict__ xh, _Float16* __restrict__ w1T, _Float16* __restrict__ w2T,
    unsigned long long* __restrict__ bmg)
{
  __shared__ __align__(16) _Float16 tile[64*72];
  const int bx = blockIdx.x;
  const int t = threadIdx.x;
  if (bx < 256) {
    const int i = bx*256 + t;
    const float4 v = ((const float4*)x)[i];
    f16x4 o; o[0]=(_Float16)v.x; o[1]=(_Float16)v.y; o[2]=(_Float16)v.z; o[3]=(_Float16)v.w;
    ((f16x4*)xh)[i] = o;
  } else if (bx < 400) {
    int ch, k0, K; const float* w; _Float16* wT;
    if (bx < 272) { ch = bx - 256; k0 = 0; K = 64; w = w1; wT = w1T; }
    else { const int u = bx - 272; ch = u >> 3; k0 = (u & 7)*64; K = 512; w = w2; wT = w2T; }
    const float* src = w + ((size_t)ch*K + k0)*64;
    #pragma unroll
    for (int j = 0; j < 4; ++j) {
      const int u = t + j*256;
      const int k = u >> 4, seg = u & 15;
      const float4 v = ((const float4*)src)[(size_t)k*16 + seg];
      tile[(seg*4+0)*72 + k] = (_Float16)v.x;
      tile[(seg*4+1)*72 + k] = (_Float16)v.y;
      tile[(seg*4+2)*72 + k] = (_Float16)v.z;
      tile[(seg*4+3)*72 + k] = (_Float16)v.w;
    }
    __syncthreads();
    _Float16* dst = wT + (size_t)ch*64*K + k0;
    #pragma unroll
    for (int j = 0; j < 2; ++j) {
      const int u = t + j*256;
      const int f = u >> 3, seg = u & 7;
      const f16x8 o = *(const f16x8*)&tile[f*72 + seg*8];
      *(f16x8*)(dst + (size_t)f*K + seg*8) = o;
    }
  } else {
    const int wg = (bx - 400)*4 + (t >> 6);
    const int lane = t & 63;
    for (int idx = wg; idx < BB*NN*16; idx += 1024) {
      const int b = idx >> 14;
      const int n = (idx >> 4) & (NN - 1);
      const int word = idx & 15;
      const int m = word*64 + lane;
      const int pred = (adj[((size_t)b*NN + n)*NN + m] != 0) || (m == n);
      unsigned long long bits = __ballot(pred);
      if (lane == 0) bmg[idx] = bits;
    }
  }
}

// ---------------- Projection via MFMA: C[32 rows][64 f] = A[rows][K] @ wT[f][K]^T ----------------
template<int K>
__global__ __launch_bounds__(256) void proj_mfma(
    const _Float16* __restrict__ A,      // [bc][N][K]
    const _Float16* __restrict__ wT,     // [c*HH+h][64][K]
    const float* __restrict__ asrc, const float* __restrict__ adst,
    _Float16* __restrict__ HpT, float* __restrict__ s_out, float* __restrict__ d_out)
{
  __shared__ float sp[4][32], sd[4][32];
  const int bch = blockIdx.y;
  const int h = bch % HH; const int bc = bch / HH; const int c = bc % CC;
  const int row0 = blockIdx.x*32;
  const int t = threadIdx.x;
  const int w = t >> 6, lane = t & 63;
  const int colr = lane & 15, quad = lane >> 4;

  const _Float16* Arow0 = A + ((size_t)bc*NN + row0 + colr)*K;
  const _Float16* Arow1 = Arow0 + (size_t)16*K;
  const _Float16* Brow  = wT + ((size_t)(c*HH + h)*64 + w*16 + colr)*K;

  f32x4 acc0 = {0.f,0.f,0.f,0.f}, acc1 = {0.f,0.f,0.f,0.f};
  #pragma unroll 4
  for (int kb = 0; kb < K; kb += 32) {
    const f16x8 a0 = *(const f16x8*)(Arow0 + kb + quad*8);
    const f16x8 a1 = *(const f16x8*)(Arow1 + kb + quad*8);
    const f16x8 bf = *(const f16x8*)(Brow  + kb + quad*8);
    acc0 = __builtin_amdgcn_mfma_f32_16x16x32_f16(a0, bf, acc0, 0, 0, 0);
    acc1 = __builtin_amdgcn_mfma_f32_16x16x32_f16(a1, bf, acc1, 0, 0, 0);
  }

  const float af = asrc[(c*HH + h)*64 + w*16 + colr];
  const float bf_ = adst[(c*HH + h)*64 + w*16 + colr];
  _Float16* HT = HpT + ((size_t)bch*64 + w*16 + colr)*NN + row0;

  #pragma unroll
  for (int mt = 0; mt < 2; ++mt) {
    const f32x4 a = mt ? acc1 : acc0;
    f16x4 hv;
    #pragma unroll
    for (int i = 0; i < 4; ++i) {
      const float v = a[i];
      hv[i] = (_Float16)v;
      const float ex = __expf(2.f*v);
      const float th = 1.f - 2.f/(ex + 1.f);         // tanh(v)
      float ps = th * af, pd = th * bf_;
      #pragma unroll
      for (int off = 1; off < 16; off <<= 1) {
        ps += __shfl_xor(ps, off);
        pd += __shfl_xor(pd, off);
      }
      if (colr == 0) {
        sp[w][mt*16 + quad*4 + i] = ps;
        sd[w][mt*16 + quad*4 + i] = pd;
      }
    }
    *(f16x4*)(HT + mt*16 + quad*4) = hv;
  }
  __syncthreads();
  if (t < 32) {
    const float sv = sp[0][t] + sp[1][t] + sp[2][t] + sp[3][t];
    const float dv = sd[0][t] + sd[1][t] + sd[2][t] + sd[3][t];
    s_out[bch*NN + row0 + t] = sv;
    d_out[bch*NN + row0 + t] = dv;
  }
}

// ---------------- Fused attention v4: 32-row blocks, XCD-swizzled grid, register P ----------
// grid (x=bch=32, y=N/32=32) -> linear%8 = bch%8 = XCD; HpT slice stays L2-local.
// 256 thr; wave w owns k-quarter [w*256,+256). Lane: rows colr & colr+16, k = quad*8 within 32-k step.
// dsum via ones-B MFMA; B/d prefetch depth 1; LDS only for the final cross-wave reduction.
template<int LAYER>
__global__ __launch_bounds__(256, 4) void attn_mfma(
    const _Float16* __restrict__ HpT, const float* __restrict__ s_arr,
    const float* __restrict__ d_arr, const unsigned long long* __restrict__ bmg,
    _Float16* __restrict__ outp)
{
  __shared__ float partials[4][32*68];   // 34.8 KB, stride 68 (2-way bank alias = free)
  __shared__ float dsP[4][32];
  const int bch = blockIdx.x;
  const int b = bch / (CC*HH);
  const int row0 = blockIdx.y*32;
  const int t = threadIdx.x;
  const int w = t >> 6, lane = t & 63;
  const int colr = lane & 15, quad = lane >> 4;

  // wave-local maxd over d[bch] (no barrier)
  const float* dg = d_arr + (size_t)bch*NN;
  const float4* dg4 = (const float4*)dg;
  float mxl = -1e30f;
  #pragma unroll
  for (int j = 0; j < 4; ++j) {
    const float4 v = dg4[lane + 64*j];
    mxl = fmaxf(fmaxf(v.x, v.y), fmaxf(fmaxf(v.z, v.w), mxl));
  }
  #pragma unroll
  for (int off = 1; off < 64; off <<= 1) mxl = fmaxf(mxl, __shfl_xor(mxl, off));
  const float maxd = mxl;

  const int r0 = row0 + colr, r1 = r0 + 16;
  const float s0 = s_arr[(size_t)bch*NN + r0];
  const float s1 = s_arr[(size_t)bch*NN + r1];
  const float so0 = s0 + maxd, so1 = s1 + maxd;
  const float offs0 = fmaxf(so0, 0.2f*so0);   // >= lrelu(s0+d) for all d
  const float offs1 = fmaxf(so1, 0.2f*so1);
  // folded lrelu-minus-offset: l-offs = max(sA + d, fma(0.2, d, sB))
  const float sA0 = s0 - offs0, sB0 = 0.2f*s0 - offs0;
  const float sA1 = s1 - offs1, sB1 = 0.2f*s1 - offs1;

  unsigned long long m0[4], m1[4];
  {
    const unsigned long long* bm0 = bmg + ((size_t)b*NN + r0)*16 + w*4;
    const unsigned long long* bm1 = bmg + ((size_t)b*NN + r1)*16 + w*4;
    #pragma unroll
    for (int j = 0; j < 4; ++j) { m0[j] = bm0[j]; m1[j] = bm1[j]; }
  }

  const _Float16* Bg = HpT + (size_t)bch*64*NN;
  const int kbase = w*256;
  const _Float16* Bp = Bg + kbase + quad*8;

  f32x4 acc[2][4], accs[2];
  #pragma unroll
  for (int rt = 0; rt < 2; ++rt) {
    accs[rt] = (f32x4){0.f,0.f,0.f,0.f};
    #pragma unroll
    for (int ft = 0; ft < 4; ++ft) acc[rt][ft] = (f32x4){0.f,0.f,0.f,0.f};
  }
  f16x8 ones;
  #pragma unroll
  for (int i = 0; i < 8; ++i) ones[i] = (_Float16)1.f;

  // prefetch ks=0
  f16x8 Bc[4];
  #pragma unroll
  for (int ft = 0; ft < 4; ++ft) Bc[ft] = *(const f16x8*)(Bp + (size_t)(ft*16 + colr)*NN);
  float4 dc0 = *(const float4*)(dg + kbase + quad*8);
  float4 dc1 = *(const float4*)(dg + kbase + quad*8 + 4);

  #pragma unroll
  for (int ks = 0; ks < 8; ++ks) {
    f16x8 Bn[4]; float4 dn0, dn1;
    if (ks < 7) {
      #pragma unroll
      for (int ft = 0; ft < 4; ++ft)
        Bn[ft] = *(const f16x8*)(Bp + (size_t)(ft*16 + colr)*NN + (ks+1)*32);
      dn0 = *(const float4*)(dg + kbase + (ks+1)*32 + quad*8);
      dn1 = *(const float4*)(dg + kbase + (ks+1)*32 + quad*8 + 4);
    }
    const unsigned mb0 = (unsigned)((m0[ks >> 1] >> ((ks & 1)*32 + quad*8)) & 0xFFull);
    const unsigned mb1 = (unsigned)((m1[ks >> 1] >> ((ks & 1)*32 + quad*8)) & 0xFFull);
    const float dd[8] = {dc0.x, dc0.y, dc0.z, dc0.w, dc1.x, dc1.y, dc1.z, dc1.w};
    union { f16x8 v; h16x2 h[4]; } A0, A1;
    #pragma unroll
    for (int jp = 0; jp < 4; ++jp) {
      float p0[2], p1[2];
      #pragma unroll
      for (int jj = 0; jj < 2; ++jj) {
        const int j = jp*2 + jj;
        const float dj = dd[j];
        const float l0 = fmaxf(sA0 + dj, fmaf(0.2f, dj, sB0));
        const float l1 = fmaxf(sA1 + dj, fmaf(0.2f, dj, sB1));
        p0[jj] = ((mb0 >> j) & 1u) ? __expf(l0) : 0.f;
        p1[jj] = ((mb1 >> j) & 1u) ? __expf(l1) : 0.f;
      }
      A0.h[jp] = __builtin_amdgcn_cvt_pkrtz(p0[0], p0[1]);
      A1.h[jp] = __builtin_amdgcn_cvt_pkrtz(p1[0], p1[1]);
    }
    #pragma unroll
    for (int ft = 0; ft < 4; ++ft) {
      acc[0][ft] = __builtin_amdgcn_mfma_f32_16x16x32_f16(A0.v, Bc[ft], acc[0][ft], 0, 0, 0);
      acc[1][ft] = __builtin_amdgcn_mfma_f32_16x16x32_f16(A1.v, Bc[ft], acc[1][ft], 0, 0, 0);
    }
    accs[0] = __builtin_amdgcn_mfma_f32_16x16x32_f16(A0.v, ones, accs[0], 0, 0, 0);
    accs[1] = __builtin_amdgcn_mfma_f32_16x16x32_f16(A1.v, ones, accs[1], 0, 0, 0);
    if (ks < 7) {
      #pragma unroll
      for (int ft = 0; ft < 4; ++ft) Bc[ft] = Bn[ft];
      dc0 = dn0; dc1 = dn1;
    }
  }

  // accs[rt][i] = this-quarter row-sum for row rt*16 + quad*4 + i (same across colr)
  if (colr == 0) {
    #pragma unroll
    for (int i = 0; i < 4; ++i) {
      dsP[w][quad*4 + i] = accs[0][i];
      dsP[w][16 + quad*4 + i] = accs[1][i];
    }
  }
  float* pw = partials[w];
  #pragma unroll
  for (int rt = 0; rt < 2; ++rt)
    #pragma unroll
    for (int ft = 0; ft < 4; ++ft)
      #pragma unroll
      for (int i = 0; i < 4; ++i)
        pw[(rt*16 + quad*4 + i)*68 + ft*16 + colr] = acc[rt][ft][i];
  __syncthreads();

  // final: thread t -> row r = t>>3, features f0 = (t&7)*8
  const int r = t >> 3, f0 = (t & 7)*8;
  const float dsum = dsP[0][r] + dsP[1][r] + dsP[2][r] + dsP[3][r];
  const float inv = 1.f / dsum;
  float4 c0 = {0.f,0.f,0.f,0.f}, c1 = {0.f,0.f,0.f,0.f};
  #pragma unroll
  for (int w4 = 0; w4 < 4; ++w4) {
    const float* base = &partials[w4][r*68 + f0];
    const float4 a0 = *(const float4*)base;
    const float4 a1 = *(const float4*)(base + 4);
    c0.x += a0.x; c0.y += a0.y; c0.z += a0.z; c0.w += a0.w;
    c1.x += a1.x; c1.y += a1.y; c1.z += a1.z; c1.w += a1.w;
  }
  const float cv[8] = {c0.x,c0.y,c0.z,c0.w, c1.x,c1.y,c1.z,c1.w};
  f16x8 o;
  #pragma unroll
  for (int i = 0; i < 8; ++i) {
    float v = cv[i] * inv;
    if (LAYER == 1) v = v > 0.f ? v : expm1f(v);
    o[i] = (_Float16)v;
  }
  const int bc = bch / HH, h = bch % HH;
  if (LAYER == 1)
    *(f16x8*)(outp + ((size_t)bc*NN + row0 + r)*512 + h*64 + f0) = o;
  else
    *(f16x8*)(outp + ((size_t)bch*NN + row0 + r)*64 + f0) = o;
}

// ---------------- Mean over heads (f16 in) -> fp32 out ----------------
__global__ __launch_bounds__(256) void reduce_heads(
    const _Float16* __restrict__ out2, float* __restrict__ out)
{
  const int o = blockIdx.x*256 + threadIdx.x;
  const int f = o & 63;
  const int n = (o >> 6) & (NN - 1);
  const int bc = o >> 16;
  float acc = 0.f;
  #pragma unroll
  for (int h = 0; h < HH; ++h)
    acc += (float)out2[(((size_t)bc*HH + h)*NN + n)*FFV + f];
  out[o] = acc * 0.125f;
}

extern "C" void kernel_launch(void* const* d_in, const int* in_sizes, int n_in,
                              void* d_out, int out_size, void* d_ws, size_t ws_size,
                              hipStream_t stream)
{
  const float* x   = (const float*)d_in[0];
  const int*   adj = (const int*)d_in[1];
  const float* w1  = (const float*)d_in[2];
  const float* as1 = (const float*)d_in[3];
  const float* ad1 = (const float*)d_in[4];
  const float* w2  = (const float*)d_in[5];
  const float* as2 = (const float*)d_in[6];
  const float* ad2 = (const float*)d_in[7];

  char* w8 = (char*)d_ws;
  _Float16* HpT = (_Float16*)(w8);                         // 4 MB  [bch][64][N]
  _Float16* XB  = (_Float16*)(w8 + (4u<<20));              // 4 MB  x1 [bc][N][512] then out2 [bch][N][64]
  _Float16* xh  = (_Float16*)(w8 + (8u<<20));              // 512 KB [bc][N][64]
  _Float16* w1T = (_Float16*)(w8 + (8u<<20) + (512u<<10)); // 128 KB [ch][64][64]
  _Float16* w2T = (_Float16*)(w8 + (8u<<20) + (768u<<10)); // 1 MB   [ch][64][512]
  float* s_v = (float*)(w8 + (10u<<20));                   // 128 KB
  float* d_v = (float*)(w8 + (10u<<20) + SVN*4);           // 128 KB
  unsigned long long* bmg = (unsigned long long*)(w8 + (10u<<20) + SVN*8);  // 256 KB

  prep_kernel<<<656, 256, 0, stream>>>(x, adj, w1, w2, xh, w1T, w2T, bmg);
  proj_mfma<64><<<dim3(NN/32, BCHN), 256, 0, stream>>>(xh, w1T, as1, ad1, HpT, s_v, d_v);
  attn_mfma<1><<<dim3(BCHN, NN/32), 256, 0, stream>>>(HpT, s_v, d_v, bmg, XB);
  proj_mfma<512><<<dim3(NN/32, BCHN), 256, 0, stream>>>(XB, w2T, as2, ad2, HpT, s_v, d_v);
  attn_mfma<2><<<dim3(BCHN, NN/32), 256, 0, stream>>>(HpT, s_v, d_v, bmg, XB);
  reduce_heads<<<dim3((unsigned)(out_size/256)), 256, 0, stream>>>(XB, (float*)d_out);
}